// Round 8
// baseline (327.930 us; speedup 1.0000x reference)
//
#include <hip/hip_runtime.h>
#include <hip/hip_bf16.h>
#include <math.h>

#define LN_EPS 1e-5f

typedef short bf16x8 __attribute__((ext_vector_type(8)));
typedef float f32x4 __attribute__((ext_vector_type(4)));

__device__ inline short f2bf(float f) {
  union { float f; unsigned u; } v; v.f = f;
  unsigned r = v.u + 0x7FFFu + ((v.u >> 16) & 1u);
  return (short)(r >> 16);
}
__device__ inline float bf2f(unsigned short s) {
  union { unsigned u; float f; } v; v.u = ((unsigned)s) << 16;
  return v.f;
}
__device__ inline float fast_exp2(float x) {
#if __has_builtin(__builtin_amdgcn_exp2f)
  return __builtin_amdgcn_exp2f(x);
#else
  return __expf(x * 0.69314718056f);
#endif
}

// ---- one-shot f32 -> bf16 conversion: Wf (65536) + Win[:512] (131072) --------
__global__ __launch_bounds__(256) void convert_kernel(const float* __restrict__ Wf,
    const float* __restrict__ Win, short* __restrict__ Wfb, short* __restrict__ Wqkb)
{
  size_t i = ((size_t)blockIdx.x * 256 + threadIdx.x) * 8;
  const float* src;
  short* dst;
  if (i < 65536) { src = Wf + i; dst = Wfb + i; }
  else { src = Win + (i - 65536); dst = Wqkb + (i - 65536); }
  f32x4 x0 = *(const f32x4*)src;
  f32x4 x1 = *(const f32x4*)(src + 4);
  bf16x8 v;
  v[0] = f2bf(x0[0]); v[1] = f2bf(x0[1]); v[2] = f2bf(x0[2]); v[3] = f2bf(x0[3]);
  v[4] = f2bf(x1[0]); v[5] = f2bf(x1[1]); v[6] = f2bf(x1[2]); v[7] = f2bf(x1[3]);
  *(bf16x8*)dst = v;
}

// ---- fused: feat@Wf^T + bf + anchor@Wa^T + ba -> LayerNorm -> tok_cur/tok_prev
// grid (384, 2): y=0 -> cur (raw anchors, t>=1), y=1 -> prev (ego, t<=10).
// W staged in LDS (shared by 4 waves); A direct global->reg with prefetch.
// Epilogue anchor-proj as 11 rank-1 sweeps (low VGPR). Target 4 blocks/CU.
__global__ __launch_bounds__(256, 4) void feat_ln(const float* __restrict__ Af,
    const short* __restrict__ Wb, const float* __restrict__ bfv,
    const float* __restrict__ anchors, const float* __restrict__ Tego,
    const float* __restrict__ Wa, const float* __restrict__ ba,
    const float* __restrict__ gamma, const float* __restrict__ beta,
    short* __restrict__ tok_cur, short* __restrict__ tok_prev)
{
  const int which = blockIdx.y;               // 0 = cur, 1 = prev
  const int row0 = blockIdx.x * 64;
  const int s24 = row0 >> 10;                 // slice = b*12 + t
  const int b = s24 / 12, t = s24 - b * 12;
  if (which == 0 && t == 0) return;
  if (which == 1 && t == 11) return;

  __shared__ short ldb[256][40];              // W tile (20.5 KB)
  __shared__ float ldWaT[11][256];            // Wa transposed (11 KB)
  __shared__ float aST[11][64];               // anchors transposed (2.8 KB)
  const int tid = threadIdx.x;
  const int wid = tid >> 6, lane = tid & 63;
  const int quad = lane >> 4, l15 = lane & 15;
  const int n0 = row0 & 1023;
  const int srow = tid >> 2, sseg = tid & 3;

  // stage Wa transposed: thread c reads Wa[c][0..10]
  {
    float wv[11];
    #pragma unroll
    for (int jj = 0; jj < 11; ++jj) wv[jj] = Wa[(size_t)tid * 11 + jj];
    #pragma unroll
    for (int jj = 0; jj < 11; ++jj) ldWaT[jj][tid] = wv[jj];
  }
  // stage this block's 64 anchor rows (raw or ego-transformed), transposed
  if (tid < 64) {
    const float* ap = anchors + ((size_t)s24 * 1024 + n0 + tid) * 11;
    float a[11];
    #pragma unroll
    for (int j = 0; j < 11; ++j) a[j] = ap[j];
    if (which == 1) {
      const float* Tm = Tego + ((size_t)b * 12 + t + 1) * 16;
      float r00 = Tm[0], r01 = Tm[1], r02 = Tm[2],  t0 = Tm[3];
      float r10 = Tm[4], r11 = Tm[5], r12 = Tm[6],  t1 = Tm[7];
      float r20 = Tm[8], r21 = Tm[9], r22 = Tm[10], t2 = Tm[11];
      float a0 = a[0], a1 = a[1], a2 = a[2];
      float a6 = a[6], a7 = a[7], a8 = a[8], a9 = a[9], a10 = a[10];
      a[0] = r00 * a0 + r01 * a1 + r02 * a2 + t0;
      a[1] = r10 * a0 + r11 * a1 + r12 * a2 + t1;
      a[2] = r20 * a0 + r21 * a1 + r22 * a2 + t2;
      a[6] = r00 * a6 + r01 * a7;
      a[7] = r10 * a6 + r11 * a7;
      a[8] = r00 * a8 + r01 * a9 + r02 * a10;
      a[9] = r10 * a8 + r11 * a9 + r12 * a10;
      a[10] = r20 * a8 + r21 * a9 + r22 * a10;
    }
    #pragma unroll
    for (int j = 0; j < 11; ++j) aST[j][tid] = a[j];
  }

  f32x4 z = {0.f, 0.f, 0.f, 0.f};
  f32x4 acc[16];
  #pragma unroll
  for (int j = 0; j < 16; ++j) acc[j] = z;

  // A fragment pointer: row = row0 + wid*16 + l15, k-chunk = quad*8 (f32)
  const float* arp = Af + (size_t)(row0 + wid * 16 + l15) * 256 + quad * 8;
  const short* wgp = Wb + (size_t)srow * 256 + sseg * 8;

  f32x4 xa0 = *(const f32x4*)(arp);
  f32x4 xa1 = *(const f32x4*)(arp + 4);

  #pragma unroll 1
  for (int ks = 0; ks < 8; ++ks) {
    const int kk = ks * 32;
    // W tile global loads (4 rows, 64 apart)
    bf16x8 w0 = *(const bf16x8*)(wgp + kk);
    bf16x8 w1 = *(const bf16x8*)(wgp + 64 * 256 + kk);
    bf16x8 w2 = *(const bf16x8*)(wgp + 128 * 256 + kk);
    bf16x8 w3 = *(const bf16x8*)(wgp + 192 * 256 + kk);
    // convert current A fragment
    bf16x8 af;
    af[0] = f2bf(xa0[0]); af[1] = f2bf(xa0[1]); af[2] = f2bf(xa0[2]); af[3] = f2bf(xa0[3]);
    af[4] = f2bf(xa1[0]); af[5] = f2bf(xa1[1]); af[6] = f2bf(xa1[2]); af[7] = f2bf(xa1[3]);
    // prefetch next A
    if (ks < 7) {
      xa0 = *(const f32x4*)(arp + kk + 32);
      xa1 = *(const f32x4*)(arp + kk + 36);
    }
    *(bf16x8*)&ldb[srow][sseg * 8]       = w0;
    *(bf16x8*)&ldb[srow + 64][sseg * 8]  = w1;
    *(bf16x8*)&ldb[srow + 128][sseg * 8] = w2;
    *(bf16x8*)&ldb[srow + 192][sseg * 8] = w3;
    __syncthreads();
    #pragma unroll
    for (int j = 0; j < 16; ++j) {
      bf16x8 bq = *(const bf16x8*)&ldb[j * 16 + l15][quad * 8];
      acc[j] = __builtin_amdgcn_mfma_f32_16x16x32_bf16(af, bq, acc[j], 0, 0, 0);
    }
    __syncthreads();
  }

  // ---- epilogue: anchor rank-1 sweeps, + (bf+ba), LN, store ----
  const int rbase = wid * 16 + quad * 4;
  #pragma unroll
  for (int jj = 0; jj < 11; ++jj) {
    f32x4 av = *(const f32x4*)&aST[jj][rbase];
    #pragma unroll
    for (int j = 0; j < 16; ++j) {
      float wv = ldWaT[jj][j * 16 + l15];
      #pragma unroll
      for (int r = 0; r < 4; ++r) acc[j][r] += wv * av[r];
    }
  }

  float s1[4] = {0.f, 0.f, 0.f, 0.f};
  float s2[4] = {0.f, 0.f, 0.f, 0.f};
  #pragma unroll
  for (int j = 0; j < 16; ++j) {
    const int col = j * 16 + l15;
    const float cb = bfv[col] + ba[col];
    #pragma unroll
    for (int r = 0; r < 4; ++r) {
      float v = acc[j][r] + cb;
      acc[j][r] = v;
      s1[r] += v; s2[r] += v * v;
    }
  }
  #pragma unroll
  for (int r = 0; r < 4; ++r) {
    #pragma unroll
    for (int off = 1; off < 16; off <<= 1) {
      s1[r] += __shfl_xor(s1[r], off);
      s2[r] += __shfl_xor(s2[r], off);
    }
  }
  float mean[4], rstd[4];
  #pragma unroll
  for (int r = 0; r < 4; ++r) {
    mean[r] = s1[r] * (1.0f / 256.0f);
    float var = s2[r] * (1.0f / 256.0f) - mean[r] * mean[r];
    rstd[r] = rsqrtf(var + LN_EPS);
  }

  short* dst = which ? tok_prev : tok_cur;
  const size_t tokbase = which ? (size_t)(b * 11 + t) * 1024
                               : (size_t)(b * 11 + t - 1) * 1024;
  #pragma unroll
  for (int j = 0; j < 16; ++j) {
    const int col = j * 16 + l15;
    const float g = gamma[col], be = beta[col];
    #pragma unroll
    for (int r = 0; r < 4; ++r) {
      const int n = n0 + wid * 16 + quad * 4 + r;
      dst[(tokbase + n) * 256 + col] = f2bf((acc[j][r] - mean[r]) * rstd[r] * g + be);
    }
  }
}

// Q/K projection fused: z=0 -> q from tok_cur (scale * log2e folded), z=1 -> k
__global__ __launch_bounds__(256) void gemm_qk(const short* __restrict__ tokc,
    const short* __restrict__ tokp, const short* __restrict__ Wqkb,
    const float* __restrict__ binv, short* __restrict__ qb, short* __restrict__ kb)
{
  const int sel = blockIdx.z;
  const short* Ap = sel ? tokp : tokc;
  const short* W = Wqkb + (size_t)sel * 65536;
  const float* bias = binv + sel * 256;
  const float alpha = sel ? 1.0f : 0.17677669529663687f * 1.4426950408889634f;
  short* Out = sel ? kb : qb;

  __shared__ short lda[128][40];
  __shared__ short ldb[128][40];
  const int tid = threadIdx.x;
  const int bm = blockIdx.x * 128, bn = blockIdx.y * 128;
  const int wid = tid >> 6, lane = tid & 63;
  const int quad = lane >> 4, l15 = lane & 15;
  const int wm = (wid & 1) * 64, wn = (wid >> 1) * 64;
  const int srow = tid >> 2, sseg = tid & 3;

  f32x4 z = {0.f, 0.f, 0.f, 0.f};
  f32x4 acc[4][4];
  #pragma unroll
  for (int i = 0; i < 4; ++i)
    #pragma unroll
    for (int j = 0; j < 4; ++j) acc[i][j] = z;

  const short* a0 = Ap + (size_t)(bm + srow) * 256 + sseg * 8;
  const short* a1 = Ap + (size_t)(bm + srow + 64) * 256 + sseg * 8;
  const short* b0 = W + (size_t)(bn + srow) * 256 + sseg * 8;
  const short* b1 = W + (size_t)(bn + srow + 64) * 256 + sseg * 8;

  for (int kk = 0; kk < 256; kk += 32) {
    *(bf16x8*)&lda[srow][sseg * 8]      = *(const bf16x8*)(a0 + kk);
    *(bf16x8*)&lda[srow + 64][sseg * 8] = *(const bf16x8*)(a1 + kk);
    *(bf16x8*)&ldb[srow][sseg * 8]      = *(const bf16x8*)(b0 + kk);
    *(bf16x8*)&ldb[srow + 64][sseg * 8] = *(const bf16x8*)(b1 + kk);
    __syncthreads();
    bf16x8 af[4], bq[4];
    #pragma unroll
    for (int i = 0; i < 4; ++i) {
      af[i] = *(const bf16x8*)&lda[wm + i * 16 + l15][quad * 8];
      bq[i] = *(const bf16x8*)&ldb[wn + i * 16 + l15][quad * 8];
    }
    #pragma unroll
    for (int i = 0; i < 4; ++i)
      #pragma unroll
      for (int j = 0; j < 4; ++j)
        acc[i][j] = __builtin_amdgcn_mfma_f32_16x16x32_bf16(af[i], bq[j], acc[i][j], 0, 0, 0);
    __syncthreads();
  }

  #pragma unroll
  for (int i = 0; i < 4; ++i)
    #pragma unroll
    for (int j = 0; j < 4; ++j)
      #pragma unroll
      for (int r = 0; r < 4; ++r) {
        int grow = bm + wm + i * 16 + quad * 4 + r;
        int gcol = bn + wn + j * 16 + l15;
        float v = (acc[i][j][r] + bias[gcol]) * alpha;
        int btr = grow >> 10, nn = grow & 1023, h = gcol >> 5, d = gcol & 31;
        Out[(((size_t)btr * 8 + h) * 1024 + nn) * 32 + d] = f2bf(v);
      }
}

// -------- pass 1: denominators; LDS-staged k; swapped mfma(k, q) ---------------
__global__ __launch_bounds__(256) void denom_kernel(const short* __restrict__ q,
  const short* __restrict__ k, float* __restrict__ dinv)
{
  __shared__ short kst[2][4096];
  const int tid = threadIdx.x, wid = tid >> 6, lane = tid & 63;
  const int quad = lane >> 4, l15 = lane & 15;
  const int h = blockIdx.y, bt = blockIdx.z;
  const int n0 = blockIdx.x * 128 + wid * 32;
  const size_t base = ((size_t)bt * 8 + h) * 32768;
  bf16x8 qf0 = *(const bf16x8*)(q + base + (size_t)(n0 + l15) * 32 + quad * 8);
  bf16x8 qf1 = *(const bf16x8*)(q + base + (size_t)(n0 + 16 + l15) * 32 + quad * 8);
  const short* ksA = k + base + (size_t)(wid * 16) * 32 + lane * 8;
  const short* ksB = k + base + (size_t)((wid + 4) * 16) * 32 + lane * 8;
  const int wswz = ((lane & 3) ^ ((lane >> 3) & 3)) * 8;
  const int rswz = (quad ^ ((l15 >> 1) & 3)) * 8;
  short* lwA = &kst[0][wid * 512 + (lane >> 2) * 32 + wswz];
  short* lwB = &kst[0][(wid + 4) * 512 + (lane >> 2) * 32 + wswz];

  f32x4 z = {0.f, 0.f, 0.f, 0.f};
  float s0 = 0.f, s1 = 0.f;

  bf16x8 stA = *(const bf16x8*)ksA;
  bf16x8 stB = *(const bf16x8*)ksB;
  *(bf16x8*)lwA = stA;
  *(bf16x8*)lwB = stB;
  __syncthreads();

  #pragma unroll 1
  for (int rd = 0; rd < 8; ++rd) {
    const int buf = rd & 1;
    if (rd < 7) {
      stA = *(const bf16x8*)(ksA + (size_t)(rd + 1) * 128 * 32);
      stB = *(const bf16x8*)(ksB + (size_t)(rd + 1) * 128 * 32);
    }
    #pragma unroll
    for (int s = 0; s < 8; ++s) {
      bf16x8 kf = *(const bf16x8*)&kst[buf][s * 512 + l15 * 32 + rswz];
      f32x4 c0 = __builtin_amdgcn_mfma_f32_16x16x32_bf16(kf, qf0, z, 0, 0, 0);
      f32x4 c1 = __builtin_amdgcn_mfma_f32_16x16x32_bf16(kf, qf1, z, 0, 0, 0);
      s0 += fast_exp2(c0[0]) + fast_exp2(c0[1]) + fast_exp2(c0[2]) + fast_exp2(c0[3]);
      s1 += fast_exp2(c1[0]) + fast_exp2(c1[1]) + fast_exp2(c1[2]) + fast_exp2(c1[3]);
    }
    if (rd < 7) {
      *(bf16x8*)(lwA + ((buf ^ 1) << 12)) = stA;
      *(bf16x8*)(lwB + ((buf ^ 1) << 12)) = stB;
    }
    __syncthreads();
  }
  s0 += __shfl_xor(s0, 16); s0 += __shfl_xor(s0, 32);
  s1 += __shfl_xor(s1, 16); s1 += __shfl_xor(s1, 32);
  if (quad == 0) {
    float* dp = dinv + ((size_t)bt * 8 + h) * 1024 + n0;
    dp[l15] = 1.f / s0;
    dp[16 + l15] = 1.f / s1;
  }
}

// -------- pass 2: probabilities + head-mean; LDS-staged k; swapped mfma --------
__global__ __launch_bounds__(256) void prob_kernel(const short* __restrict__ q,
  const short* __restrict__ k, const float* __restrict__ dinv, float* __restrict__ out)
{
  __shared__ short kst[2][4096];
  const int tid = threadIdx.x, wid = tid >> 6, lane = tid & 63;
  const int quad = lane >> 4, l15 = lane & 15;
  const int bt = blockIdx.z;
  const int n0 = blockIdx.x * 128 + wid * 32;
  const int mbase = blockIdx.y * 128;
  const int b = bt / 11, t = bt - b * 11;

  bf16x8 qf0[8], qf1[8];
  float invd0[8], invd1[8];
  #pragma unroll
  for (int h = 0; h < 8; ++h) {
    const size_t base = ((size_t)bt * 8 + h) * 32768;
    qf0[h] = *(const bf16x8*)(q + base + (size_t)(n0 + l15) * 32 + quad * 8);
    qf1[h] = *(const bf16x8*)(q + base + (size_t)(n0 + 16 + l15) * 32 + quad * 8);
    invd0[h] = dinv[((size_t)bt * 8 + h) * 1024 + n0 + l15] * 0.125f;
    invd1[h] = dinv[((size_t)bt * 8 + h) * 1024 + n0 + 16 + l15] * 0.125f;
  }
  const short* ksA = k + (((size_t)bt * 8 + wid    ) * 1024 + mbase) * 32 + lane * 8;
  const short* ksB = k + (((size_t)bt * 8 + wid + 4) * 1024 + mbase) * 32 + lane * 8;
  const int wswz = ((lane & 3) ^ ((lane >> 3) & 3)) * 8;
  const int rswz = (quad ^ ((l15 >> 1) & 3)) * 8;
  short* lwA = &kst[0][wid * 512 + (lane >> 2) * 32 + wswz];
  short* lwB = &kst[0][(wid + 4) * 512 + (lane >> 2) * 32 + wswz];

  float* ob0 = out + ((size_t)(b * 12 + t + 1) * 1024 + n0 + l15) * 1024
                   + mbase + quad * 4;
  float* ob1 = ob0 + (size_t)16 * 1024;
  f32x4 z = {0.f, 0.f, 0.f, 0.f};

  bf16x8 stA = *(const bf16x8*)ksA;
  bf16x8 stB = *(const bf16x8*)ksB;
  *(bf16x8*)lwA = stA;
  *(bf16x8*)lwB = stB;
  __syncthreads();

  #pragma unroll 1
  for (int mt = 0; mt < 8; ++mt) {
    const int buf = mt & 1;
    if (mt < 7) {
      stA = *(const bf16x8*)(ksA + (size_t)(mt + 1) * 16 * 32);
      stB = *(const bf16x8*)(ksB + (size_t)(mt + 1) * 16 * 32);
    }
    f32x4 P0 = z, P1 = z;
    #pragma unroll
    for (int h = 0; h < 8; ++h) {
      bf16x8 kf = *(const bf16x8*)&kst[buf][h * 512 + l15 * 32 + rswz];
      f32x4 c0 = __builtin_amdgcn_mfma_f32_16x16x32_bf16(kf, qf0[h], z, 0, 0, 0);
      f32x4 c1 = __builtin_amdgcn_mfma_f32_16x16x32_bf16(kf, qf1[h], z, 0, 0, 0);
      #pragma unroll
      for (int r = 0; r < 4; ++r) {
        P0[r] += fast_exp2(c0[r]) * invd0[h];
        P1[r] += fast_exp2(c1[r]) * invd1[h];
      }
    }
    *(f32x4*)(ob0 + mt * 16) = P0;
    *(f32x4*)(ob1 + mt * 16) = P1;
    if (mt < 7) {
      *(bf16x8*)(lwA + ((buf ^ 1) << 12)) = stA;
      *(bf16x8*)(lwB + ((buf ^ 1) << 12)) = stB;
    }
    __syncthreads();
  }
}

// -------------- identity slab at t=0 -------------------------------------------
__global__ __launch_bounds__(256) void eye_kernel(float* __restrict__ out) {
  int gid = blockIdx.x * 256 + threadIdx.x;
  int b = gid >> 18, rem = gid & 262143;
  int n = rem >> 8, m4 = rem & 255;
  f32x4 v = {0.f, 0.f, 0.f, 0.f};
  int c = n - m4 * 4;
  if (c >= 0 && c < 4) v[c] = 1.0f;
  *(f32x4*)(out + (size_t)b * 12582912 + (size_t)n * 1024 + m4 * 4) = v;
}

extern "C" void kernel_launch(void* const* d_in, const int* in_sizes, int n_in,
                              void* d_out, int out_size, void* d_ws, size_t ws_size,
                              hipStream_t stream)
{
  const float* sf   = (const float*)d_in[0];
  const float* sa   = (const float*)d_in[1];
  const float* te   = (const float*)d_in[2];
  const float* Wf   = (const float*)d_in[3];
  const float* bfv  = (const float*)d_in[4];
  const float* Wa   = (const float*)d_in[5];
  const float* ba   = (const float*)d_in[6];
  const float* Win  = (const float*)d_in[7];
  const float* binv = (const float*)d_in[8];
  const float* gam  = (const float*)d_in[9];
  const float* bet  = (const float*)d_in[10];
  float* out = (float*)d_out;

  char* w = (char*)d_ws;
  short* tok_cur  = (short*)w;  w += 11534336;
  short* tok_prev = (short*)w;  w += 11534336;
  short* qb       = (short*)w;  w += 11534336;
  short* kb       = (short*)w;  w += 11534336;
  float* dinv     = (float*)w;  w += 720896;
  short* Wfb      = (short*)w;  w += 131072;
  short* Wqkb     = (short*)w;  w += 262144;

  convert_kernel<<<dim3(96), 256, 0, stream>>>(Wf, Win, Wfb, Wqkb);
  feat_ln<<<dim3(384, 2), 256, 0, stream>>>(sf, Wfb, bfv, sa, te, Wa, ba, gam, bet,
                                            tok_cur, tok_prev);
  gemm_qk<<<dim3(176, 2, 2), 256, 0, stream>>>(tok_cur, tok_prev, Wqkb, binv, qb, kb);
  denom_kernel<<<dim3(8, 8, 22), 256, 0, stream>>>(qb, kb, dinv);
  prob_kernel<<<dim3(8, 8, 22), 256, 0, stream>>>(qb, kb, dinv, out);
  eye_kernel<<<dim3(2048), 256, 0, stream>>>(out);
}

// Round 9
// 247.844 us; speedup vs baseline: 1.3231x; 1.3231x over previous
//
#include <hip/hip_runtime.h>
#include <hip/hip_bf16.h>
#include <math.h>

#define LN_EPS 1e-5f

typedef short bf16x8 __attribute__((ext_vector_type(8)));
typedef float f32x4 __attribute__((ext_vector_type(4)));

__device__ inline short f2bf(float f) {
  union { float f; unsigned u; } v; v.f = f;
  unsigned r = v.u + 0x7FFFu + ((v.u >> 16) & 1u);
  return (short)(r >> 16);
}
__device__ inline float bf2f(unsigned short s) {
  union { unsigned u; float f; } v; v.u = ((unsigned)s) << 16;
  return v.f;
}
__device__ inline float fast_exp2(float x) {
#if __has_builtin(__builtin_amdgcn_exp2f)
  return __builtin_amdgcn_exp2f(x);
#else
  return __expf(x * 0.69314718056f);
#endif
}

// ---- one-shot f32 -> bf16 conversion: Wf (65536) + Win[:512] (131072) --------
__global__ __launch_bounds__(256) void convert_kernel(const float* __restrict__ Wf,
    const float* __restrict__ Win, short* __restrict__ Wfb, short* __restrict__ Wqkb)
{
  size_t i = ((size_t)blockIdx.x * 256 + threadIdx.x) * 8;
  const float* src;
  short* dst;
  if (i < 65536) { src = Wf + i; dst = Wfb + i; }
  else { src = Win + (i - 65536); dst = Wqkb + (i - 65536); }
  f32x4 x0 = *(const f32x4*)src;
  f32x4 x1 = *(const f32x4*)(src + 4);
  bf16x8 v;
  v[0] = f2bf(x0[0]); v[1] = f2bf(x0[1]); v[2] = f2bf(x0[2]); v[3] = f2bf(x0[3]);
  v[4] = f2bf(x1[0]); v[5] = f2bf(x1[1]); v[6] = f2bf(x1[2]); v[7] = f2bf(x1[3]);
  *(bf16x8*)dst = v;
}

// ---- fused: feat@Wf^T + bf + anchor@Wa^T + ba -> LayerNorm -> tok_cur/tok_prev
// grid (384, 2): y=0 -> cur (raw anchors, t>=1), y=1 -> prev (ego, t<=10).
// W staged in LDS (shared by 4 waves); A direct global->reg with prefetch.
// Epilogue anchor-proj as 11 rank-1 sweeps. launch_bounds(256,2): NO spill
// (R8's (256,4) forced VGPR=64 -> acc[16] spilled to scratch, 470 MB traffic).
__global__ __launch_bounds__(256, 2) void feat_ln(const float* __restrict__ Af,
    const short* __restrict__ Wb, const float* __restrict__ bfv,
    const float* __restrict__ anchors, const float* __restrict__ Tego,
    const float* __restrict__ Wa, const float* __restrict__ ba,
    const float* __restrict__ gamma, const float* __restrict__ beta,
    short* __restrict__ tok_cur, short* __restrict__ tok_prev)
{
  const int which = blockIdx.y;               // 0 = cur, 1 = prev
  const int row0 = blockIdx.x * 64;
  const int s24 = row0 >> 10;                 // slice = b*12 + t
  const int b = s24 / 12, t = s24 - b * 12;
  if (which == 0 && t == 0) return;
  if (which == 1 && t == 11) return;

  __shared__ short ldb[256][40];              // W tile (20.5 KB)
  __shared__ float ldWaT[11][256];            // Wa transposed (11 KB)
  __shared__ float aST[11][64];               // anchors transposed (2.8 KB)
  const int tid = threadIdx.x;
  const int wid = tid >> 6, lane = tid & 63;
  const int quad = lane >> 4, l15 = lane & 15;
  const int n0 = row0 & 1023;
  const int srow = tid >> 2, sseg = tid & 3;

  // stage Wa transposed: thread c reads Wa[c][0..10]
  {
    float wv[11];
    #pragma unroll
    for (int jj = 0; jj < 11; ++jj) wv[jj] = Wa[(size_t)tid * 11 + jj];
    #pragma unroll
    for (int jj = 0; jj < 11; ++jj) ldWaT[jj][tid] = wv[jj];
  }
  // stage this block's 64 anchor rows (raw or ego-transformed), transposed
  if (tid < 64) {
    const float* ap = anchors + ((size_t)s24 * 1024 + n0 + tid) * 11;
    float a[11];
    #pragma unroll
    for (int j = 0; j < 11; ++j) a[j] = ap[j];
    if (which == 1) {
      const float* Tm = Tego + ((size_t)b * 12 + t + 1) * 16;
      float r00 = Tm[0], r01 = Tm[1], r02 = Tm[2],  t0 = Tm[3];
      float r10 = Tm[4], r11 = Tm[5], r12 = Tm[6],  t1 = Tm[7];
      float r20 = Tm[8], r21 = Tm[9], r22 = Tm[10], t2 = Tm[11];
      float a0 = a[0], a1 = a[1], a2 = a[2];
      float a6 = a[6], a7 = a[7], a8 = a[8], a9 = a[9], a10 = a[10];
      a[0] = r00 * a0 + r01 * a1 + r02 * a2 + t0;
      a[1] = r10 * a0 + r11 * a1 + r12 * a2 + t1;
      a[2] = r20 * a0 + r21 * a1 + r22 * a2 + t2;
      a[6] = r00 * a6 + r01 * a7;
      a[7] = r10 * a6 + r11 * a7;
      a[8] = r00 * a8 + r01 * a9 + r02 * a10;
      a[9] = r10 * a8 + r11 * a9 + r12 * a10;
      a[10] = r20 * a8 + r21 * a9 + r22 * a10;
    }
    #pragma unroll
    for (int j = 0; j < 11; ++j) aST[j][tid] = a[j];
  }

  f32x4 z = {0.f, 0.f, 0.f, 0.f};
  f32x4 acc[16];
  #pragma unroll
  for (int j = 0; j < 16; ++j) acc[j] = z;

  // A fragment pointer: row = row0 + wid*16 + l15, k-chunk = quad*8 (f32)
  const float* arp = Af + (size_t)(row0 + wid * 16 + l15) * 256 + quad * 8;
  const short* wgp = Wb + (size_t)srow * 256 + sseg * 8;

  f32x4 xa0 = *(const f32x4*)(arp);
  f32x4 xa1 = *(const f32x4*)(arp + 4);

  #pragma unroll 1
  for (int ks = 0; ks < 8; ++ks) {
    const int kk = ks * 32;
    // W tile global loads (4 rows, 64 apart)
    bf16x8 w0 = *(const bf16x8*)(wgp + kk);
    bf16x8 w1 = *(const bf16x8*)(wgp + 64 * 256 + kk);
    bf16x8 w2 = *(const bf16x8*)(wgp + 128 * 256 + kk);
    bf16x8 w3 = *(const bf16x8*)(wgp + 192 * 256 + kk);
    // convert current A fragment
    bf16x8 af;
    af[0] = f2bf(xa0[0]); af[1] = f2bf(xa0[1]); af[2] = f2bf(xa0[2]); af[3] = f2bf(xa0[3]);
    af[4] = f2bf(xa1[0]); af[5] = f2bf(xa1[1]); af[6] = f2bf(xa1[2]); af[7] = f2bf(xa1[3]);
    // prefetch next A
    if (ks < 7) {
      xa0 = *(const f32x4*)(arp + kk + 32);
      xa1 = *(const f32x4*)(arp + kk + 36);
    }
    *(bf16x8*)&ldb[srow][sseg * 8]       = w0;
    *(bf16x8*)&ldb[srow + 64][sseg * 8]  = w1;
    *(bf16x8*)&ldb[srow + 128][sseg * 8] = w2;
    *(bf16x8*)&ldb[srow + 192][sseg * 8] = w3;
    __syncthreads();
    #pragma unroll
    for (int j = 0; j < 16; ++j) {
      bf16x8 bq = *(const bf16x8*)&ldb[j * 16 + l15][quad * 8];
      acc[j] = __builtin_amdgcn_mfma_f32_16x16x32_bf16(af, bq, acc[j], 0, 0, 0);
    }
    __syncthreads();
  }

  // ---- epilogue: anchor rank-1 sweeps, + (bf+ba), LN, store ----
  const int rbase = wid * 16 + quad * 4;
  #pragma unroll
  for (int jj = 0; jj < 11; ++jj) {
    f32x4 av = *(const f32x4*)&aST[jj][rbase];
    #pragma unroll
    for (int j = 0; j < 16; ++j) {
      float wv = ldWaT[jj][j * 16 + l15];
      #pragma unroll
      for (int r = 0; r < 4; ++r) acc[j][r] += wv * av[r];
    }
  }

  float s1[4] = {0.f, 0.f, 0.f, 0.f};
  float s2[4] = {0.f, 0.f, 0.f, 0.f};
  #pragma unroll
  for (int j = 0; j < 16; ++j) {
    const int col = j * 16 + l15;
    const float cb = bfv[col] + ba[col];
    #pragma unroll
    for (int r = 0; r < 4; ++r) {
      float v = acc[j][r] + cb;
      acc[j][r] = v;
      s1[r] += v; s2[r] += v * v;
    }
  }
  #pragma unroll
  for (int r = 0; r < 4; ++r) {
    #pragma unroll
    for (int off = 1; off < 16; off <<= 1) {
      s1[r] += __shfl_xor(s1[r], off);
      s2[r] += __shfl_xor(s2[r], off);
    }
  }
  float mean[4], rstd[4];
  #pragma unroll
  for (int r = 0; r < 4; ++r) {
    mean[r] = s1[r] * (1.0f / 256.0f);
    float var = s2[r] * (1.0f / 256.0f) - mean[r] * mean[r];
    rstd[r] = rsqrtf(var + LN_EPS);
  }

  short* dst = which ? tok_prev : tok_cur;
  const size_t tokbase = which ? (size_t)(b * 11 + t) * 1024
                               : (size_t)(b * 11 + t - 1) * 1024;
  #pragma unroll
  for (int j = 0; j < 16; ++j) {
    const int col = j * 16 + l15;
    const float g = gamma[col], be = beta[col];
    #pragma unroll
    for (int r = 0; r < 4; ++r) {
      const int n = n0 + wid * 16 + quad * 4 + r;
      dst[(tokbase + n) * 256 + col] = f2bf((acc[j][r] - mean[r]) * rstd[r] * g + be);
    }
  }
}

// Q/K projection fused: z=0 -> q from tok_cur (scale * log2e folded), z=1 -> k
__global__ __launch_bounds__(256) void gemm_qk(const short* __restrict__ tokc,
    const short* __restrict__ tokp, const short* __restrict__ Wqkb,
    const float* __restrict__ binv, short* __restrict__ qb, short* __restrict__ kb)
{
  const int sel = blockIdx.z;
  const short* Ap = sel ? tokp : tokc;
  const short* W = Wqkb + (size_t)sel * 65536;
  const float* bias = binv + sel * 256;
  const float alpha = sel ? 1.0f : 0.17677669529663687f * 1.4426950408889634f;
  short* Out = sel ? kb : qb;

  __shared__ short lda[128][40];
  __shared__ short ldb[128][40];
  const int tid = threadIdx.x;
  const int bm = blockIdx.x * 128, bn = blockIdx.y * 128;
  const int wid = tid >> 6, lane = tid & 63;
  const int quad = lane >> 4, l15 = lane & 15;
  const int wm = (wid & 1) * 64, wn = (wid >> 1) * 64;
  const int srow = tid >> 2, sseg = tid & 3;

  f32x4 z = {0.f, 0.f, 0.f, 0.f};
  f32x4 acc[4][4];
  #pragma unroll
  for (int i = 0; i < 4; ++i)
    #pragma unroll
    for (int j = 0; j < 4; ++j) acc[i][j] = z;

  const short* a0 = Ap + (size_t)(bm + srow) * 256 + sseg * 8;
  const short* a1 = Ap + (size_t)(bm + srow + 64) * 256 + sseg * 8;
  const short* b0 = W + (size_t)(bn + srow) * 256 + sseg * 8;
  const short* b1 = W + (size_t)(bn + srow + 64) * 256 + sseg * 8;

  for (int kk = 0; kk < 256; kk += 32) {
    *(bf16x8*)&lda[srow][sseg * 8]      = *(const bf16x8*)(a0 + kk);
    *(bf16x8*)&lda[srow + 64][sseg * 8] = *(const bf16x8*)(a1 + kk);
    *(bf16x8*)&ldb[srow][sseg * 8]      = *(const bf16x8*)(b0 + kk);
    *(bf16x8*)&ldb[srow + 64][sseg * 8] = *(const bf16x8*)(b1 + kk);
    __syncthreads();
    bf16x8 af[4], bq[4];
    #pragma unroll
    for (int i = 0; i < 4; ++i) {
      af[i] = *(const bf16x8*)&lda[wm + i * 16 + l15][quad * 8];
      bq[i] = *(const bf16x8*)&ldb[wn + i * 16 + l15][quad * 8];
    }
    #pragma unroll
    for (int i = 0; i < 4; ++i)
      #pragma unroll
      for (int j = 0; j < 4; ++j)
        acc[i][j] = __builtin_amdgcn_mfma_f32_16x16x32_bf16(af[i], bq[j], acc[i][j], 0, 0, 0);
    __syncthreads();
  }

  #pragma unroll
  for (int i = 0; i < 4; ++i)
    #pragma unroll
    for (int j = 0; j < 4; ++j)
      #pragma unroll
      for (int r = 0; r < 4; ++r) {
        int grow = bm + wm + i * 16 + quad * 4 + r;
        int gcol = bn + wn + j * 16 + l15;
        float v = (acc[i][j][r] + bias[gcol]) * alpha;
        int btr = grow >> 10, nn = grow & 1023, h = gcol >> 5, d = gcol & 31;
        Out[(((size_t)btr * 8 + h) * 1024 + nn) * 32 + d] = f2bf(v);
      }
}

// -------- pass 1: denominators; LDS-staged k; swapped mfma(k, q) ---------------
__global__ __launch_bounds__(256) void denom_kernel(const short* __restrict__ q,
  const short* __restrict__ k, float* __restrict__ dinv)
{
  __shared__ short kst[2][4096];
  const int tid = threadIdx.x, wid = tid >> 6, lane = tid & 63;
  const int quad = lane >> 4, l15 = lane & 15;
  const int h = blockIdx.y, bt = blockIdx.z;
  const int n0 = blockIdx.x * 128 + wid * 32;
  const size_t base = ((size_t)bt * 8 + h) * 32768;
  bf16x8 qf0 = *(const bf16x8*)(q + base + (size_t)(n0 + l15) * 32 + quad * 8);
  bf16x8 qf1 = *(const bf16x8*)(q + base + (size_t)(n0 + 16 + l15) * 32 + quad * 8);
  const short* ksA = k + base + (size_t)(wid * 16) * 32 + lane * 8;
  const short* ksB = k + base + (size_t)((wid + 4) * 16) * 32 + lane * 8;
  const int wswz = ((lane & 3) ^ ((lane >> 3) & 3)) * 8;
  const int rswz = (quad ^ ((l15 >> 1) & 3)) * 8;
  short* lwA = &kst[0][wid * 512 + (lane >> 2) * 32 + wswz];
  short* lwB = &kst[0][(wid + 4) * 512 + (lane >> 2) * 32 + wswz];

  f32x4 z = {0.f, 0.f, 0.f, 0.f};
  float s0 = 0.f, s1 = 0.f;

  bf16x8 stA = *(const bf16x8*)ksA;
  bf16x8 stB = *(const bf16x8*)ksB;
  *(bf16x8*)lwA = stA;
  *(bf16x8*)lwB = stB;
  __syncthreads();

  #pragma unroll 1
  for (int rd = 0; rd < 8; ++rd) {
    const int buf = rd & 1;
    if (rd < 7) {
      stA = *(const bf16x8*)(ksA + (size_t)(rd + 1) * 128 * 32);
      stB = *(const bf16x8*)(ksB + (size_t)(rd + 1) * 128 * 32);
    }
    #pragma unroll
    for (int s = 0; s < 8; ++s) {
      bf16x8 kf = *(const bf16x8*)&kst[buf][s * 512 + l15 * 32 + rswz];
      f32x4 c0 = __builtin_amdgcn_mfma_f32_16x16x32_bf16(kf, qf0, z, 0, 0, 0);
      f32x4 c1 = __builtin_amdgcn_mfma_f32_16x16x32_bf16(kf, qf1, z, 0, 0, 0);
      s0 += fast_exp2(c0[0]) + fast_exp2(c0[1]) + fast_exp2(c0[2]) + fast_exp2(c0[3]);
      s1 += fast_exp2(c1[0]) + fast_exp2(c1[1]) + fast_exp2(c1[2]) + fast_exp2(c1[3]);
    }
    if (rd < 7) {
      *(bf16x8*)(lwA + ((buf ^ 1) << 12)) = stA;
      *(bf16x8*)(lwB + ((buf ^ 1) << 12)) = stB;
    }
    __syncthreads();
  }
  s0 += __shfl_xor(s0, 16); s0 += __shfl_xor(s0, 32);
  s1 += __shfl_xor(s1, 16); s1 += __shfl_xor(s1, 32);
  if (quad == 0) {
    float* dp = dinv + ((size_t)bt * 8 + h) * 1024 + n0;
    dp[l15] = 1.f / s0;
    dp[16 + l15] = 1.f / s1;
  }
}

// -------- pass 2: probabilities + head-mean; LDS-staged k; swapped mfma --------
__global__ __launch_bounds__(256) void prob_kernel(const short* __restrict__ q,
  const short* __restrict__ k, const float* __restrict__ dinv, float* __restrict__ out)
{
  __shared__ short kst[2][4096];
  const int tid = threadIdx.x, wid = tid >> 6, lane = tid & 63;
  const int quad = lane >> 4, l15 = lane & 15;
  const int bt = blockIdx.z;
  const int n0 = blockIdx.x * 128 + wid * 32;
  const int mbase = blockIdx.y * 128;
  const int b = bt / 11, t = bt - b * 11;

  bf16x8 qf0[8], qf1[8];
  float invd0[8], invd1[8];
  #pragma unroll
  for (int h = 0; h < 8; ++h) {
    const size_t base = ((size_t)bt * 8 + h) * 32768;
    qf0[h] = *(const bf16x8*)(q + base + (size_t)(n0 + l15) * 32 + quad * 8);
    qf1[h] = *(const bf16x8*)(q + base + (size_t)(n0 + 16 + l15) * 32 + quad * 8);
    invd0[h] = dinv[((size_t)bt * 8 + h) * 1024 + n0 + l15] * 0.125f;
    invd1[h] = dinv[((size_t)bt * 8 + h) * 1024 + n0 + 16 + l15] * 0.125f;
  }
  const short* ksA = k + (((size_t)bt * 8 + wid    ) * 1024 + mbase) * 32 + lane * 8;
  const short* ksB = k + (((size_t)bt * 8 + wid + 4) * 1024 + mbase) * 32 + lane * 8;
  const int wswz = ((lane & 3) ^ ((lane >> 3) & 3)) * 8;
  const int rswz = (quad ^ ((l15 >> 1) & 3)) * 8;
  short* lwA = &kst[0][wid * 512 + (lane >> 2) * 32 + wswz];
  short* lwB = &kst[0][(wid + 4) * 512 + (lane >> 2) * 32 + wswz];

  float* ob0 = out + ((size_t)(b * 12 + t + 1) * 1024 + n0 + l15) * 1024
                   + mbase + quad * 4;
  float* ob1 = ob0 + (size_t)16 * 1024;
  f32x4 z = {0.f, 0.f, 0.f, 0.f};

  bf16x8 stA = *(const bf16x8*)ksA;
  bf16x8 stB = *(const bf16x8*)ksB;
  *(bf16x8*)lwA = stA;
  *(bf16x8*)lwB = stB;
  __syncthreads();

  #pragma unroll 1
  for (int mt = 0; mt < 8; ++mt) {
    const int buf = mt & 1;
    if (mt < 7) {
      stA = *(const bf16x8*)(ksA + (size_t)(mt + 1) * 16 * 32);
      stB = *(const bf16x8*)(ksB + (size_t)(mt + 1) * 16 * 32);
    }
    f32x4 P0 = z, P1 = z;
    #pragma unroll
    for (int h = 0; h < 8; ++h) {
      bf16x8 kf = *(const bf16x8*)&kst[buf][h * 512 + l15 * 32 + rswz];
      f32x4 c0 = __builtin_amdgcn_mfma_f32_16x16x32_bf16(kf, qf0[h], z, 0, 0, 0);
      f32x4 c1 = __builtin_amdgcn_mfma_f32_16x16x32_bf16(kf, qf1[h], z, 0, 0, 0);
      #pragma unroll
      for (int r = 0; r < 4; ++r) {
        P0[r] += fast_exp2(c0[r]) * invd0[h];
        P1[r] += fast_exp2(c1[r]) * invd1[h];
      }
    }
    *(f32x4*)(ob0 + mt * 16) = P0;
    *(f32x4*)(ob1 + mt * 16) = P1;
    if (mt < 7) {
      *(bf16x8*)(lwA + ((buf ^ 1) << 12)) = stA;
      *(bf16x8*)(lwB + ((buf ^ 1) << 12)) = stB;
    }
    __syncthreads();
  }
}

// -------------- identity slab at t=0 -------------------------------------------
__global__ __launch_bounds__(256) void eye_kernel(float* __restrict__ out) {
  int gid = blockIdx.x * 256 + threadIdx.x;
  int b = gid >> 18, rem = gid & 262143;
  int n = rem >> 8, m4 = rem & 255;
  f32x4 v = {0.f, 0.f, 0.f, 0.f};
  int c = n - m4 * 4;
  if (c >= 0 && c < 4) v[c] = 1.0f;
  *(f32x4*)(out + (size_t)b * 12582912 + (size_t)n * 1024 + m4 * 4) = v;
}

extern "C" void kernel_launch(void* const* d_in, const int* in_sizes, int n_in,
                              void* d_out, int out_size, void* d_ws, size_t ws_size,
                              hipStream_t stream)
{
  const float* sf   = (const float*)d_in[0];
  const float* sa   = (const float*)d_in[1];
  const float* te   = (const float*)d_in[2];
  const float* Wf   = (const float*)d_in[3];
  const float* bfv  = (const float*)d_in[4];
  const float* Wa   = (const float*)d_in[5];
  const float* ba   = (const float*)d_in[6];
  const float* Win  = (const float*)d_in[7];
  const float* binv = (const float*)d_in[8];
  const float* gam  = (const float*)d_in[9];
  const float* bet  = (const float*)d_in[10];
  float* out = (float*)d_out;

  char* w = (char*)d_ws;
  short* tok_cur  = (short*)w;  w += 11534336;
  short* tok_prev = (short*)w;  w += 11534336;
  short* qb       = (short*)w;  w += 11534336;
  short* kb       = (short*)w;  w += 11534336;
  float* dinv     = (float*)w;  w += 720896;
  short* Wfb      = (short*)w;  w += 131072;
  short* Wqkb     = (short*)w;  w += 262144;

  convert_kernel<<<dim3(96), 256, 0, stream>>>(Wf, Win, Wfb, Wqkb);
  feat_ln<<<dim3(384, 2), 256, 0, stream>>>(sf, Wfb, bfv, sa, te, Wa, ba, gam, bet,
                                            tok_cur, tok_prev);
  gemm_qk<<<dim3(176, 2, 2), 256, 0, stream>>>(tok_cur, tok_prev, Wqkb, binv, qb, kb);
  denom_kernel<<<dim3(8, 8, 22), 256, 0, stream>>>(qb, kb, dinv);
  prob_kernel<<<dim3(8, 8, 22), 256, 0, stream>>>(qb, kb, dinv, out);
  eye_kernel<<<dim3(2048), 256, 0, stream>>>(out);
}

// Round 10
// 245.232 us; speedup vs baseline: 1.3372x; 1.0107x over previous
//
#include <hip/hip_runtime.h>
#include <hip/hip_bf16.h>
#include <math.h>

#define LN_EPS 1e-5f

typedef short bf16x8 __attribute__((ext_vector_type(8)));
typedef float f32x4 __attribute__((ext_vector_type(4)));

__device__ inline short f2bf(float f) {
  union { float f; unsigned u; } v; v.f = f;
  unsigned r = v.u + 0x7FFFu + ((v.u >> 16) & 1u);
  return (short)(r >> 16);
}
__device__ inline float bf2f(unsigned short s) {
  union { unsigned u; float f; } v; v.u = ((unsigned)s) << 16;
  return v.f;
}
__device__ inline float fast_exp2(float x) {
#if __has_builtin(__builtin_amdgcn_exp2f)
  return __builtin_amdgcn_exp2f(x);
#else
  return __expf(x * 0.69314718056f);
#endif
}

// ---- one-shot f32 -> bf16 conversion: Wf (65536) + Win[:512] (131072) --------
__global__ __launch_bounds__(256) void convert_kernel(const float* __restrict__ Wf,
    const float* __restrict__ Win, short* __restrict__ Wfb, short* __restrict__ Wqkb)
{
  size_t i = ((size_t)blockIdx.x * 256 + threadIdx.x) * 8;
  const float* src;
  short* dst;
  if (i < 65536) { src = Wf + i; dst = Wfb + i; }
  else { src = Win + (i - 65536); dst = Wqkb + (i - 65536); }
  f32x4 x0 = *(const f32x4*)src;
  f32x4 x1 = *(const f32x4*)(src + 4);
  bf16x8 v;
  v[0] = f2bf(x0[0]); v[1] = f2bf(x0[1]); v[2] = f2bf(x0[2]); v[3] = f2bf(x0[3]);
  v[4] = f2bf(x1[0]); v[5] = f2bf(x1[1]); v[6] = f2bf(x1[2]); v[7] = f2bf(x1[3]);
  *(bf16x8*)dst = v;
}

// ---- fused: feat@Wf^T + bf + anchor@Wa^T + ba -> LayerNorm -> tok_cur/tok_prev
// grid (384): ONE GEMM per 64-row slab, then dual emit (cur if t>=1, prev if t<=10)
// with the cheap rank-1 epilogue into a reusable d[16] register block.
__global__ __launch_bounds__(256, 2) void feat_ln(const float* __restrict__ Af,
    const short* __restrict__ Wb, const float* __restrict__ bfv,
    const float* __restrict__ anchors, const float* __restrict__ Tego,
    const float* __restrict__ Wa, const float* __restrict__ ba,
    const float* __restrict__ gamma, const float* __restrict__ beta,
    short* __restrict__ tok_cur, short* __restrict__ tok_prev)
{
  const int row0 = blockIdx.x * 64;
  const int s24 = row0 >> 10;                 // slice = b*12 + t
  const int b = s24 / 12, t = s24 - b * 12;

  __shared__ short ldb[256][40];              // W tile (20.5 KB)
  __shared__ float ldWaT[11][256];            // Wa transposed (11 KB)
  __shared__ float aSTc[11][64];              // raw anchors, transposed
  __shared__ float aSTp[11][64];              // ego-transformed anchors
  __shared__ float cbS[256];                  // bf + ba
  const int tid = threadIdx.x;
  const int wid = tid >> 6, lane = tid & 63;
  const int quad = lane >> 4, l15 = lane & 15;
  const int n0 = row0 & 1023;
  const int srow = tid >> 2, sseg = tid & 3;

  cbS[tid] = bfv[tid] + ba[tid];
  // stage Wa transposed: thread c reads Wa[c][0..10]
  {
    float wv[11];
    #pragma unroll
    for (int jj = 0; jj < 11; ++jj) wv[jj] = Wa[(size_t)tid * 11 + jj];
    #pragma unroll
    for (int jj = 0; jj < 11; ++jj) ldWaT[jj][tid] = wv[jj];
  }
  // stage this block's 64 anchor rows: raw (cur) + ego-transformed (prev)
  if (tid < 64) {
    const float* ap = anchors + ((size_t)s24 * 1024 + n0 + tid) * 11;
    float a[11];
    #pragma unroll
    for (int j = 0; j < 11; ++j) a[j] = ap[j];
    #pragma unroll
    for (int j = 0; j < 11; ++j) aSTc[j][tid] = a[j];
    if (t <= 10) {
      const float* Tm = Tego + ((size_t)b * 12 + t + 1) * 16;
      float r00 = Tm[0], r01 = Tm[1], r02 = Tm[2],  t0 = Tm[3];
      float r10 = Tm[4], r11 = Tm[5], r12 = Tm[6],  t1 = Tm[7];
      float r20 = Tm[8], r21 = Tm[9], r22 = Tm[10], t2 = Tm[11];
      float p0 = r00 * a[0] + r01 * a[1] + r02 * a[2] + t0;
      float p1 = r10 * a[0] + r11 * a[1] + r12 * a[2] + t1;
      float p2 = r20 * a[0] + r21 * a[1] + r22 * a[2] + t2;
      float p6 = r00 * a[6] + r01 * a[7];
      float p7 = r10 * a[6] + r11 * a[7];
      float p8 = r00 * a[8] + r01 * a[9] + r02 * a[10];
      float p9 = r10 * a[8] + r11 * a[9] + r12 * a[10];
      float p10 = r20 * a[8] + r21 * a[9] + r22 * a[10];
      aSTp[0][tid] = p0;  aSTp[1][tid] = p1;  aSTp[2][tid] = p2;
      aSTp[3][tid] = a[3]; aSTp[4][tid] = a[4]; aSTp[5][tid] = a[5];
      aSTp[6][tid] = p6;  aSTp[7][tid] = p7;
      aSTp[8][tid] = p8;  aSTp[9][tid] = p9;  aSTp[10][tid] = p10;
    }
  }

  f32x4 z = {0.f, 0.f, 0.f, 0.f};
  f32x4 acc[16];
  #pragma unroll
  for (int j = 0; j < 16; ++j) acc[j] = z;

  // A fragment pointer: row = row0 + wid*16 + l15, k-chunk = quad*8 (f32)
  const float* arp = Af + (size_t)(row0 + wid * 16 + l15) * 256 + quad * 8;
  const short* wgp = Wb + (size_t)srow * 256 + sseg * 8;

  f32x4 xa0 = *(const f32x4*)(arp);
  f32x4 xa1 = *(const f32x4*)(arp + 4);

  #pragma unroll 1
  for (int ks = 0; ks < 8; ++ks) {
    const int kk = ks * 32;
    bf16x8 w0 = *(const bf16x8*)(wgp + kk);
    bf16x8 w1 = *(const bf16x8*)(wgp + 64 * 256 + kk);
    bf16x8 w2 = *(const bf16x8*)(wgp + 128 * 256 + kk);
    bf16x8 w3 = *(const bf16x8*)(wgp + 192 * 256 + kk);
    bf16x8 af;
    af[0] = f2bf(xa0[0]); af[1] = f2bf(xa0[1]); af[2] = f2bf(xa0[2]); af[3] = f2bf(xa0[3]);
    af[4] = f2bf(xa1[0]); af[5] = f2bf(xa1[1]); af[6] = f2bf(xa1[2]); af[7] = f2bf(xa1[3]);
    if (ks < 7) {
      xa0 = *(const f32x4*)(arp + kk + 32);
      xa1 = *(const f32x4*)(arp + kk + 36);
    }
    *(bf16x8*)&ldb[srow][sseg * 8]       = w0;
    *(bf16x8*)&ldb[srow + 64][sseg * 8]  = w1;
    *(bf16x8*)&ldb[srow + 128][sseg * 8] = w2;
    *(bf16x8*)&ldb[srow + 192][sseg * 8] = w3;
    __syncthreads();
    #pragma unroll
    for (int j = 0; j < 16; ++j) {
      bf16x8 bq = *(const bf16x8*)&ldb[j * 16 + l15][quad * 8];
      acc[j] = __builtin_amdgcn_mfma_f32_16x16x32_bf16(af, bq, acc[j], 0, 0, 0);
    }
    __syncthreads();
  }

  // ---- dual emit: d[16] = anchor@Wa^T (rank-1 sweeps), v = acc+cb+d, LN, store
  const int rbase = wid * 16 + quad * 4;
  auto emit = [&](const float (*aST)[64], short* dst, size_t tokbase) {
    f32x4 d[16];
    #pragma unroll
    for (int j = 0; j < 16; ++j) d[j] = z;
    #pragma unroll
    for (int jj = 0; jj < 11; ++jj) {
      f32x4 av = *(const f32x4*)&aST[jj][rbase];
      #pragma unroll
      for (int j = 0; j < 16; ++j) {
        float wv = ldWaT[jj][j * 16 + l15];
        #pragma unroll
        for (int r = 0; r < 4; ++r) d[j][r] += wv * av[r];
      }
    }
    float s1[4] = {0.f, 0.f, 0.f, 0.f};
    float s2[4] = {0.f, 0.f, 0.f, 0.f};
    #pragma unroll
    for (int j = 0; j < 16; ++j) {
      const float cb = cbS[j * 16 + l15];
      #pragma unroll
      for (int r = 0; r < 4; ++r) {
        float v = acc[j][r] + cb + d[j][r];
        d[j][r] = v;
        s1[r] += v; s2[r] += v * v;
      }
    }
    #pragma unroll
    for (int r = 0; r < 4; ++r) {
      #pragma unroll
      for (int off = 1; off < 16; off <<= 1) {
        s1[r] += __shfl_xor(s1[r], off);
        s2[r] += __shfl_xor(s2[r], off);
      }
    }
    float mean[4], rstd[4];
    #pragma unroll
    for (int r = 0; r < 4; ++r) {
      mean[r] = s1[r] * (1.0f / 256.0f);
      float var = s2[r] * (1.0f / 256.0f) - mean[r] * mean[r];
      rstd[r] = rsqrtf(var + LN_EPS);
    }
    #pragma unroll
    for (int j = 0; j < 16; ++j) {
      const int col = j * 16 + l15;
      const float g = gamma[col], be = beta[col];
      #pragma unroll
      for (int r = 0; r < 4; ++r) {
        const int n = n0 + wid * 16 + quad * 4 + r;
        dst[(tokbase + n) * 256 + col] = f2bf((d[j][r] - mean[r]) * rstd[r] * g + be);
      }
    }
  };

  if (t >= 1)  emit(aSTc, tok_cur,  (size_t)(b * 11 + t - 1) * 1024);
  if (t <= 10) emit(aSTp, tok_prev, (size_t)(b * 11 + t) * 1024);
}

// Q/K projection fused: z=0 -> q (scale*log2e folded), z=1 -> k.
// Swapped mfma(bq, af): reg dim walks gcol -> each lane stores 4 consecutive
// d-values as one aligned short4 (16 stores/lane instead of 64 scalar shorts).
__global__ __launch_bounds__(256) void gemm_qk(const short* __restrict__ tokc,
    const short* __restrict__ tokp, const short* __restrict__ Wqkb,
    const float* __restrict__ binv, short* __restrict__ qb, short* __restrict__ kb)
{
  const int sel = blockIdx.z;
  const short* Ap = sel ? tokp : tokc;
  const short* W = Wqkb + (size_t)sel * 65536;
  const float* bias = binv + sel * 256;
  const float alpha = sel ? 1.0f : 0.17677669529663687f * 1.4426950408889634f;
  short* Out = sel ? kb : qb;

  __shared__ short lda[128][40];
  __shared__ short ldb[128][40];
  const int tid = threadIdx.x;
  const int bm = blockIdx.x * 128, bn = blockIdx.y * 128;
  const int wid = tid >> 6, lane = tid & 63;
  const int quad = lane >> 4, l15 = lane & 15;
  const int wm = (wid & 1) * 64, wn = (wid >> 1) * 64;
  const int srow = tid >> 2, sseg = tid & 3;

  f32x4 z = {0.f, 0.f, 0.f, 0.f};
  f32x4 acc[4][4];
  #pragma unroll
  for (int i = 0; i < 4; ++i)
    #pragma unroll
    for (int j = 0; j < 4; ++j) acc[i][j] = z;

  const short* a0 = Ap + (size_t)(bm + srow) * 256 + sseg * 8;
  const short* a1 = Ap + (size_t)(bm + srow + 64) * 256 + sseg * 8;
  const short* b0 = W + (size_t)(bn + srow) * 256 + sseg * 8;
  const short* b1 = W + (size_t)(bn + srow + 64) * 256 + sseg * 8;

  for (int kk = 0; kk < 256; kk += 32) {
    *(bf16x8*)&lda[srow][sseg * 8]      = *(const bf16x8*)(a0 + kk);
    *(bf16x8*)&lda[srow + 64][sseg * 8] = *(const bf16x8*)(a1 + kk);
    *(bf16x8*)&ldb[srow][sseg * 8]      = *(const bf16x8*)(b0 + kk);
    *(bf16x8*)&ldb[srow + 64][sseg * 8] = *(const bf16x8*)(b1 + kk);
    __syncthreads();
    bf16x8 af[4], bq[4];
    #pragma unroll
    for (int i = 0; i < 4; ++i) {
      af[i] = *(const bf16x8*)&lda[wm + i * 16 + l15][quad * 8];
      bq[i] = *(const bf16x8*)&ldb[wn + i * 16 + l15][quad * 8];
    }
    #pragma unroll
    for (int i = 0; i < 4; ++i)
      #pragma unroll
      for (int j = 0; j < 4; ++j)
        acc[i][j] = __builtin_amdgcn_mfma_f32_16x16x32_bf16(bq[j], af[i], acc[i][j], 0, 0, 0);
    __syncthreads();
  }

  // epilogue: lane owns row grow = bm+wm+i*16+l15; regs walk gcol.
  #pragma unroll
  for (int i = 0; i < 4; ++i) {
    const int grow = bm + wm + i * 16 + l15;
    const int btr = grow >> 10, nn = grow & 1023;
    #pragma unroll
    for (int j = 0; j < 4; ++j) {
      const int gcol0 = bn + wn + j * 16;
      const int h = gcol0 >> 5;
      const int d0 = (gcol0 & 31) + quad * 4;
      f32x4 bv = *(const f32x4*)(bias + gcol0 + quad * 4);
      short4 o;
      o.x = f2bf((acc[i][j][0] + bv[0]) * alpha);
      o.y = f2bf((acc[i][j][1] + bv[1]) * alpha);
      o.z = f2bf((acc[i][j][2] + bv[2]) * alpha);
      o.w = f2bf((acc[i][j][3] + bv[3]) * alpha);
      *(short4*)(Out + (((size_t)btr * 8 + h) * 1024 + nn) * 32 + d0) = o;
    }
  }
}

// -------- pass 1: denominators; LDS-staged k; swapped mfma(k, q) ---------------
__global__ __launch_bounds__(256) void denom_kernel(const short* __restrict__ q,
  const short* __restrict__ k, float* __restrict__ dinv)
{
  __shared__ short kst[2][4096];
  const int tid = threadIdx.x, wid = tid >> 6, lane = tid & 63;
  const int quad = lane >> 4, l15 = lane & 15;
  const int h = blockIdx.y, bt = blockIdx.z;
  const int n0 = blockIdx.x * 128 + wid * 32;
  const size_t base = ((size_t)bt * 8 + h) * 32768;
  bf16x8 qf0 = *(const bf16x8*)(q + base + (size_t)(n0 + l15) * 32 + quad * 8);
  bf16x8 qf1 = *(const bf16x8*)(q + base + (size_t)(n0 + 16 + l15) * 32 + quad * 8);
  const short* ksA = k + base + (size_t)(wid * 16) * 32 + lane * 8;
  const short* ksB = k + base + (size_t)((wid + 4) * 16) * 32 + lane * 8;
  const int wswz = ((lane & 3) ^ ((lane >> 3) & 3)) * 8;
  const int rswz = (quad ^ ((l15 >> 1) & 3)) * 8;
  short* lwA = &kst[0][wid * 512 + (lane >> 2) * 32 + wswz];
  short* lwB = &kst[0][(wid + 4) * 512 + (lane >> 2) * 32 + wswz];

  f32x4 z = {0.f, 0.f, 0.f, 0.f};
  float s0 = 0.f, s1 = 0.f;

  bf16x8 stA = *(const bf16x8*)ksA;
  bf16x8 stB = *(const bf16x8*)ksB;
  *(bf16x8*)lwA = stA;
  *(bf16x8*)lwB = stB;
  __syncthreads();

  #pragma unroll 1
  for (int rd = 0; rd < 8; ++rd) {
    const int buf = rd & 1;
    if (rd < 7) {
      stA = *(const bf16x8*)(ksA + (size_t)(rd + 1) * 128 * 32);
      stB = *(const bf16x8*)(ksB + (size_t)(rd + 1) * 128 * 32);
    }
    #pragma unroll
    for (int s = 0; s < 8; ++s) {
      bf16x8 kf = *(const bf16x8*)&kst[buf][s * 512 + l15 * 32 + rswz];
      f32x4 c0 = __builtin_amdgcn_mfma_f32_16x16x32_bf16(kf, qf0, z, 0, 0, 0);
      f32x4 c1 = __builtin_amdgcn_mfma_f32_16x16x32_bf16(kf, qf1, z, 0, 0, 0);
      s0 += fast_exp2(c0[0]) + fast_exp2(c0[1]) + fast_exp2(c0[2]) + fast_exp2(c0[3]);
      s1 += fast_exp2(c1[0]) + fast_exp2(c1[1]) + fast_exp2(c1[2]) + fast_exp2(c1[3]);
    }
    if (rd < 7) {
      *(bf16x8*)(lwA + ((buf ^ 1) << 12)) = stA;
      *(bf16x8*)(lwB + ((buf ^ 1) << 12)) = stB;
    }
    __syncthreads();
  }
  s0 += __shfl_xor(s0, 16); s0 += __shfl_xor(s0, 32);
  s1 += __shfl_xor(s1, 16); s1 += __shfl_xor(s1, 32);
  if (quad == 0) {
    float* dp = dinv + ((size_t)bt * 8 + h) * 1024 + n0;
    dp[l15] = 1.f / s0;
    dp[16 + l15] = 1.f / s1;
  }
}

// -------- pass 2: probabilities + head-mean; LDS-staged k; swapped mfma --------
__global__ __launch_bounds__(256) void prob_kernel(const short* __restrict__ q,
  const short* __restrict__ k, const float* __restrict__ dinv, float* __restrict__ out)
{
  __shared__ short kst[2][4096];
  const int tid = threadIdx.x, wid = tid >> 6, lane = tid & 63;
  const int quad = lane >> 4, l15 = lane & 15;
  const int bt = blockIdx.z;
  const int n0 = blockIdx.x * 128 + wid * 32;
  const int mbase = blockIdx.y * 128;
  const int b = bt / 11, t = bt - b * 11;

  bf16x8 qf0[8], qf1[8];
  float invd0[8], invd1[8];
  #pragma unroll
  for (int h = 0; h < 8; ++h) {
    const size_t base = ((size_t)bt * 8 + h) * 32768;
    qf0[h] = *(const bf16x8*)(q + base + (size_t)(n0 + l15) * 32 + quad * 8);
    qf1[h] = *(const bf16x8*)(q + base + (size_t)(n0 + 16 + l15) * 32 + quad * 8);
    invd0[h] = dinv[((size_t)bt * 8 + h) * 1024 + n0 + l15] * 0.125f;
    invd1[h] = dinv[((size_t)bt * 8 + h) * 1024 + n0 + 16 + l15] * 0.125f;
  }
  const short* ksA = k + (((size_t)bt * 8 + wid    ) * 1024 + mbase) * 32 + lane * 8;
  const short* ksB = k + (((size_t)bt * 8 + wid + 4) * 1024 + mbase) * 32 + lane * 8;
  const int wswz = ((lane & 3) ^ ((lane >> 3) & 3)) * 8;
  const int rswz = (quad ^ ((l15 >> 1) & 3)) * 8;
  short* lwA = &kst[0][wid * 512 + (lane >> 2) * 32 + wswz];
  short* lwB = &kst[0][(wid + 4) * 512 + (lane >> 2) * 32 + wswz];

  float* ob0 = out + ((size_t)(b * 12 + t + 1) * 1024 + n0 + l15) * 1024
                   + mbase + quad * 4;
  float* ob1 = ob0 + (size_t)16 * 1024;
  f32x4 z = {0.f, 0.f, 0.f, 0.f};

  bf16x8 stA = *(const bf16x8*)ksA;
  bf16x8 stB = *(const bf16x8*)ksB;
  *(bf16x8*)lwA = stA;
  *(bf16x8*)lwB = stB;
  __syncthreads();

  #pragma unroll 1
  for (int mt = 0; mt < 8; ++mt) {
    const int buf = mt & 1;
    if (mt < 7) {
      stA = *(const bf16x8*)(ksA + (size_t)(mt + 1) * 16 * 32);
      stB = *(const bf16x8*)(ksB + (size_t)(mt + 1) * 16 * 32);
    }
    f32x4 P0 = z, P1 = z;
    #pragma unroll
    for (int h = 0; h < 8; ++h) {
      bf16x8 kf = *(const bf16x8*)&kst[buf][h * 512 + l15 * 32 + rswz];
      f32x4 c0 = __builtin_amdgcn_mfma_f32_16x16x32_bf16(kf, qf0[h], z, 0, 0, 0);
      f32x4 c1 = __builtin_amdgcn_mfma_f32_16x16x32_bf16(kf, qf1[h], z, 0, 0, 0);
      #pragma unroll
      for (int r = 0; r < 4; ++r) {
        P0[r] += fast_exp2(c0[r]) * invd0[h];
        P1[r] += fast_exp2(c1[r]) * invd1[h];
      }
    }
    *(f32x4*)(ob0 + mt * 16) = P0;
    *(f32x4*)(ob1 + mt * 16) = P1;
    if (mt < 7) {
      *(bf16x8*)(lwA + ((buf ^ 1) << 12)) = stA;
      *(bf16x8*)(lwB + ((buf ^ 1) << 12)) = stB;
    }
    __syncthreads();
  }
}

// -------------- identity slab at t=0 -------------------------------------------
__global__ __launch_bounds__(256) void eye_kernel(float* __restrict__ out) {
  int gid = blockIdx.x * 256 + threadIdx.x;
  int b = gid >> 18, rem = gid & 262143;
  int n = rem >> 8, m4 = rem & 255;
  f32x4 v = {0.f, 0.f, 0.f, 0.f};
  int c = n - m4 * 4;
  if (c >= 0 && c < 4) v[c] = 1.0f;
  *(f32x4*)(out + (size_t)b * 12582912 + (size_t)n * 1024 + m4 * 4) = v;
}

extern "C" void kernel_launch(void* const* d_in, const int* in_sizes, int n_in,
                              void* d_out, int out_size, void* d_ws, size_t ws_size,
                              hipStream_t stream)
{
  const float* sf   = (const float*)d_in[0];
  const float* sa   = (const float*)d_in[1];
  const float* te   = (const float*)d_in[2];
  const float* Wf   = (const float*)d_in[3];
  const float* bfv  = (const float*)d_in[4];
  const float* Wa   = (const float*)d_in[5];
  const float* ba   = (const float*)d_in[6];
  const float* Win  = (const float*)d_in[7];
  const float* binv = (const float*)d_in[8];
  const float* gam  = (const float*)d_in[9];
  const float* bet  = (const float*)d_in[10];
  float* out = (float*)d_out;

  char* w = (char*)d_ws;
  short* tok_cur  = (short*)w;  w += 11534336;
  short* tok_prev = (short*)w;  w += 11534336;
  short* qb       = (short*)w;  w += 11534336;
  short* kb       = (short*)w;  w += 11534336;
  float* dinv     = (float*)w;  w += 720896;
  short* Wfb      = (short*)w;  w += 131072;
  short* Wqkb     = (short*)w;  w += 262144;

  convert_kernel<<<dim3(96), 256, 0, stream>>>(Wf, Win, Wfb, Wqkb);
  feat_ln<<<dim3(384), 256, 0, stream>>>(sf, Wfb, bfv, sa, te, Wa, ba, gam, bet,
                                         tok_cur, tok_prev);
  gemm_qk<<<dim3(176, 2, 2), 256, 0, stream>>>(tok_cur, tok_prev, Wqkb, binv, qb, kb);
  denom_kernel<<<dim3(8, 8, 22), 256, 0, stream>>>(qb, kb, dinv);
  prob_kernel<<<dim3(8, 8, 22), 256, 0, stream>>>(qb, kb, dinv, out);
  eye_kernel<<<dim3(2048), 256, 0, stream>>>(out);
}